// Round 7
// baseline (29.324 us; speedup 1.0000x reference)
//
#include <hip/hip_runtime.h>
#include <math.h>

#define R_ 1.3f
#define NCOARSE 32
#define SAMPLES 383
#define BATCH 512
#define STEPSZ 0.0203125f                  // 2*1.3/32/2/2
#define INV_FINE_VLEN 24.615384615384617f  // 64 / 2.6

using f32x4 = __attribute__((ext_vector_type(4))) float;
using s16x8 = __attribute__((ext_vector_type(8))) short;
using u32x4 = __attribute__((ext_vector_type(4))) unsigned int;
using bf16x2 = __attribute__((ext_vector_type(2))) __bf16;

// f32 pair -> packed bf16 (RNE); compiler emits v_cvt_pk_bf16_f32.
__device__ __forceinline__ unsigned int packbf2(float lo, float hi) {
    bf16x2 v;
    v.x = (__bf16)lo;
    v.y = (__bf16)hi;
    return __builtin_bit_cast(unsigned int, v);
}

// Per-dim: summed weight W[t] and coarse index C[t] for fine-parity t.
__device__ __forceinline__ void dimwc(float p, float* W, int* C) {
    float post0 = fminf(fmaxf(floorf(p - 0.5f), 0.f), 63.f);
    float post1 = fminf(fmaxf(floorf(p + 0.5f), 0.f), 63.f);
    float w0 = 1.f - fabsf(p - (post0 + 0.5f));
    float w1 = 1.f - fabsf(p - (post1 + 0.5f));
    int i0 = (int)post0, i1 = (int)post1;
    int f0 = i0 & 1, f1 = i1 & 1;
    W[0] = (f0 == 0 ? w0 : 0.f) + (f1 == 0 ? w1 : 0.f);
    W[1] = (f0 == 1 ? w0 : 0.f) + (f1 == 1 ? w1 : 0.f);
    int c0 = i0 >> 1, c1 = i1 >> 1;
    C[0] = (f0 == 0) ? c0 : c1;
    C[1] = (f0 == 1) ? c0 : c1;
}

// One ray per block, 8 waves. Software-pipelined half-tile gathers:
// a 4-corner gather is always in flight under pack/MFMA/epilogue.
__global__ __launch_bounds__(512, 4) void dp_fused(
    const float* __restrict__ rays_o, const float* __restrict__ rays_d,
    const float* __restrict__ grid, const float* __restrict__ atoms,
    float* __restrict__ out_rgb, float* __restrict__ out_alpha,
    float* __restrict__ out_depth, float* __restrict__ out_loss)
{
    __shared__ u32x4 Bf[16][64];        // 16 KB: B fragments (block-shared)
    __shared__ float Dw[8][544];        // 8 waves x 2176 B: D staging (stride 33)
    __shared__ float alpha_l[384];
    __shared__ float sig_l[384][3];
    __shared__ float sh_s[9];
    __shared__ float segtot[8];
    __shared__ float part[6][5];

    const int b = blockIdx.x;
    const int tid = threadIdx.x;
    const int wid = tid >> 6, l = tid & 63;
    const int sl = l & 15, j8 = (l >> 4) * 8;

    // ---- B-build atom loads FIRST (latency merged with tile-0 gathers) ----
    const int s0i = tid, s1i = tid + 512;
    const int ll0 = s0i & 63, nt0 = (s0i >> 6) & 1, kb0 = s0i >> 7;
    const int ll1 = s1i & 63, nt1 = (s1i >> 6) & 1, kb1 = s1i >> 7;
    const int a00 = (ll0 >> 4) * 8, d0 = nt0 * 16 + (ll0 & 15);
    const int a01 = (ll1 >> 4) * 8, d1 = nt1 * 16 + (ll1 & 15);
    float la0[8], la1[8];
#pragma unroll
    for (int j = 0; j < 8; ++j) {
        la0[j] = (d0 < 28) ? atoms[(kb0 * 32 + a00 + j) * 28 + d0] : 0.f;
        la1[j] = (d1 < 28) ? atoms[(kb1 * 32 + a01 + j) * 28 + d1] : 0.f;
    }

    if (b == 0 && tid == 0) out_loss[0] = 0.f;

    // ---- zero alpha/sig staging ----
    if (tid < 384) alpha_l[tid] = 0.f;
    {
        float* sf = &sig_l[0][0];
        for (int i = tid; i < 384 * 3; i += 512) sf[i] = 0.f;
    }

    // ---- ray setup (block-uniform) ----
    const float ox = rays_o[3 * b], oy = rays_o[3 * b + 1], oz = rays_o[3 * b + 2];
    const float dx = rays_d[3 * b], dy = rays_d[3 * b + 1], dz = rays_d[3 * b + 2];
    const float start = fmaxf(fmaxf(
        fminf((R_ - ox) / dx, (-R_ - ox) / dx),
        fminf((R_ - oy) / dy, (-R_ - oy) / dy)),
        fminf((R_ - oz) / dz, (-R_ - oz) / dz));
    const float t_exit = fminf(fminf(
        fmaxf((R_ - ox) / dx, (-R_ - ox) / dx),
        fmaxf((R_ - oy) / dy, (-R_ - oy) / dy)),
        fmaxf((R_ - oz) / dz, (-R_ - oz) / dz));
    const int ns = (int)floorf((t_exit - start) / STEPSZ) + 2;
    const int ntiles = min(24, (ns >> 4) + 2);

    const float lend = sqrtf(dx * dx + dy * dy + dz * dz);
    const float dist = STEPSZ * lend;

    if (tid == 0) {   // SH basis -> LDS (block-uniform, saves VGPRs)
        const float inv = 1.f / lend;
        const float nx = dx * inv, ny = dy * inv, nz = dz * inv;
        sh_s[0] = 0.28209479177387814f;
        sh_s[1] = -0.48860251190291987f * ny;
        sh_s[2] = 0.48860251190291987f * nz;
        sh_s[3] = -0.48860251190291987f * nx;
        sh_s[4] = 1.0925484305920792f * nx * ny;
        sh_s[5] = -1.0925484305920792f * ny * nz;
        sh_s[6] = 0.31539156525252005f * (2.f * nz * nz - nx * nx - ny * ny);
        sh_s[7] = -1.0925484305920792f * nx * nz;
        sh_s[8] = 0.5462742152960396f * (nx * nx - ny * ny);
    }

    // ---- pipeline helpers ----
    auto computeWC = [&](int t, float Wx[2], float Wy[2], float Wz[2],
                         int Cx[2], int Cy[2], int Cz[2]) -> float {
        const int s = t * 16 + sl;
        const float tt = start + s * STEPSZ;
        const float px = ox + tt * dx, py = oy + tt * dy, pz = oz + tt * dz;
        const bool m = (s < SAMPLES) &&
                       (px > -R_ && px < R_ && py > -R_ && py < R_ && pz > -R_ && pz < R_);
        dimwc((px + R_) * INV_FINE_VLEN, Wx, Cx);
        dimwc((py + R_) * INV_FINE_VLEN, Wy, Cy);
        dimwc((pz + R_) * INV_FINE_VLEN, Wz, Cz);
        return m ? 1.f : 0.f;
    };
    auto issueHalf = [&](int h, const int Cx[2], const int Cy[2], const int Cz[2],
                         f32x4 qa[4], f32x4 qb[4]) {
#pragma unroll
        for (int k2 = 0; k2 < 4; ++k2) {
            const int kb = h + k2;
            const int fx = (kb >> 2) & 1, fy = (kb >> 1) & 1, fz = kb & 1;
            const int cf = (Cx[fx] * NCOARSE + Cy[fy]) * NCOARSE + Cz[fz];
            const f32x4* gp = (const f32x4*)(grid + cf * 32 + j8);
            qa[k2] = gp[0];
            qb[k2] = gp[1];
        }
    };
    auto consumeHalf = [&](int h, float msk,
                           const float Wx[2], const float Wy[2], const float Wz[2],
                           const f32x4 qa[4], const f32x4 qb[4],
                           f32x4& acc0, f32x4& acc1) {
#pragma unroll
        for (int k2 = 0; k2 < 4; ++k2) {
            const int kb = h + k2;
            const float w = msk * Wx[(kb >> 2) & 1] * Wy[(kb >> 1) & 1] * Wz[kb & 1];
            u32x4 o;
            o.x = packbf2(w * qa[k2].x, w * qa[k2].y);
            o.y = packbf2(w * qa[k2].z, w * qa[k2].w);
            o.z = packbf2(w * qb[k2].x, w * qb[k2].y);
            o.w = packbf2(w * qb[k2].z, w * qb[k2].w);
            const s16x8 af = __builtin_bit_cast(s16x8, o);
            acc0 = __builtin_amdgcn_mfma_f32_16x16x32_bf16(
                af, __builtin_bit_cast(s16x8, Bf[kb * 2 + 0][l]), acc0, 0, 0, 0);
            acc1 = __builtin_amdgcn_mfma_f32_16x16x32_bf16(
                af, __builtin_bit_cast(s16x8, Bf[kb * 2 + 1][l]), acc1, 0, 0, 0);
        }
    };
    float* Dbuf = &Dw[wid][0];
    auto epilogue = [&](int t, const f32x4& acc0, const f32x4& acc1) {
        const int fp = l >> 4;
#pragma unroll
        for (int r = 0; r < 4; ++r) {
            Dbuf[(4 * fp + r) * 33 + sl]      = acc0[r];
            Dbuf[(4 * fp + r) * 33 + sl + 16] = acc1[r];
        }
        const int s2 = l >> 2, c = l & 3;
        const int so = t * 16 + s2;
        if (c == 3) {
            const float sigma = fmaxf(Dbuf[s2 * 33 + 27], 0.f);
            alpha_l[so] = 1.f - __expf(-sigma * dist);
        } else {
            float r_ = 0.f;
#pragma unroll
            for (int k = 0; k < 9; ++k) r_ += sh_s[k] * Dbuf[s2 * 33 + c * 9 + k];
            sig_l[so][c] = __builtin_amdgcn_rcpf(1.f + __expf(-r_));
        }
    };

    // wave-uniform tile validity (no ballot needed; masked samples contribute 0)
    const bool v0 = wid < ntiles, v1 = wid + 8 < ntiles, v2 = wid + 16 < ntiles;

    float WxA[2], WyA[2], WzA[2], WxB[2], WyB[2], WzB[2];
    int CxA[2], CyA[2], CzA[2], CxB[2], CyB[2], CzB[2];
    float mskA = 0.f, mskB = 0.f;
    f32x4 ga[4], gb[4], ha[4], hb[4];   // ping/pong 4-corner gather buffers

    // ---- pre-sync: issue tile-0 half-0 (drains together with atom loads) ----
    if (v0) {
        mskA = computeWC(wid, WxA, WyA, WzA, CxA, CyA, CzA);
        issueHalf(0, CxA, CyA, CzA, ga, gb);
    }

    // ---- pack + store B fragments ----
    {
        u32x4 o0, o1;
#pragma unroll
        for (int e2 = 0; e2 < 4; ++e2) {
            o0[e2] = packbf2(la0[2 * e2], la0[2 * e2 + 1]);
            o1[e2] = packbf2(la1[2 * e2], la1[2 * e2 + 1]);
        }
        Bf[s0i >> 6][ll0] = o0;
        Bf[s1i >> 6][ll1] = o1;
    }

    __syncthreads();   // Bf + zeroed staging + sh_s visible; all loads drained

    // ---- pipelined sample phase ----
    if (v0) {
        f32x4 acc0 = {0.f, 0.f, 0.f, 0.f};
        f32x4 acc1 = {0.f, 0.f, 0.f, 0.f};
        issueHalf(4, CxA, CyA, CzA, ha, hb);
        consumeHalf(0, mskA, WxA, WyA, WzA, ga, gb, acc0, acc1);
        if (v1) {
            mskB = computeWC(wid + 8, WxB, WyB, WzB, CxB, CyB, CzB);
            issueHalf(0, CxB, CyB, CzB, ga, gb);
        }
        consumeHalf(4, mskA, WxA, WyA, WzA, ha, hb, acc0, acc1);
        epilogue(wid, acc0, acc1);
        if (v1) {
            acc0 = {0.f, 0.f, 0.f, 0.f};
            acc1 = {0.f, 0.f, 0.f, 0.f};
            issueHalf(4, CxB, CyB, CzB, ha, hb);
            consumeHalf(0, mskB, WxB, WyB, WzB, ga, gb, acc0, acc1);
            if (v2) {
                mskA = computeWC(wid + 16, WxA, WyA, WzA, CxA, CyA, CzA);
                issueHalf(0, CxA, CyA, CzA, ga, gb);
            }
            consumeHalf(4, mskB, WxB, WyB, WzB, ha, hb, acc0, acc1);
            epilogue(wid + 8, acc0, acc1);
            if (v2) {
                acc0 = {0.f, 0.f, 0.f, 0.f};
                acc1 = {0.f, 0.f, 0.f, 0.f};
                issueHalf(4, CxA, CyA, CzA, ha, hb);
                consumeHalf(0, mskA, WxA, WyA, WzA, ga, gb, acc0, acc1);
                consumeHalf(4, mskA, WxA, WyA, WzA, ha, hb, acc0, acc1);
                epilogue(wid + 16, acc0, acc1);
            }
        }
    }

    __syncthreads();

    // coalesced alpha store
    if (tid < SAMPLES) out_alpha[b * SAMPLES + tid] = alpha_l[tid];

    // ---- parallel compositing: 6 waves each scan a 64-sample segment ----
    float a_s = 0.f, incl = 1.f;
    if (wid < 6) {
        const int s = wid * 64 + l;
        const bool v = s < SAMPLES;
        a_s = v ? alpha_l[s] : 0.f;
        incl = v ? (1.f - a_s + 1e-10f) : 1.f;
#pragma unroll
        for (int off = 1; off < 64; off <<= 1) {
            const float tm = __shfl_up(incl, off, 64);
            if (l >= off) incl *= tm;
        }
        if (l == 63) segtot[wid] = incl;
    }
    __syncthreads();
    if (wid < 6) {
        float pre = 1.f;
        for (int k = 0; k < wid; ++k) pre *= segtot[k];   // wave-uniform
        float excl = __shfl_up(incl, 1, 64);
        if (l == 0) excl = 1.f;
        const int s = wid * 64 + l;
        const bool v = s < SAMPLES;
        const float al = v ? a_s * pre * excl : 0.f;
        float r0 = al * sig_l[s][0];
        float r1 = al * sig_l[s][1];
        float r2 = al * sig_l[s][2];
        float sd = al * (start + s * STEPSZ);
        float sa = al;
#pragma unroll
        for (int m2 = 32; m2 > 0; m2 >>= 1) {
            r0 += __shfl_xor(r0, m2, 64);
            r1 += __shfl_xor(r1, m2, 64);
            r2 += __shfl_xor(r2, m2, 64);
            sd += __shfl_xor(sd, m2, 64);
            sa += __shfl_xor(sa, m2, 64);
        }
        if (l == 0) {
            part[wid][0] = r0; part[wid][1] = r1; part[wid][2] = r2;
            part[wid][3] = sd; part[wid][4] = sa;
        }
    }
    __syncthreads();
    if (tid == 0) {
        float r0 = 0.f, r1 = 0.f, r2 = 0.f, sd = 0.f, sa = 0.f;
#pragma unroll
        for (int j = 0; j < 6; ++j) {
            r0 += part[j][0]; r1 += part[j][1]; r2 += part[j][2];
            sd += part[j][3]; sa += part[j][4];
        }
        const float base = 1.f - sa;
        out_rgb[b * 3 + 0] = r0 + base;
        out_rgb[b * 3 + 1] = r1 + base;
        out_rgb[b * 3 + 2] = r2 + base;
        out_depth[b] = sd;
    }
}

extern "C" void kernel_launch(void* const* d_in, const int* in_sizes, int n_in,
                              void* d_out, int out_size, void* d_ws, size_t ws_size,
                              hipStream_t stream) {
    const float* rays_o = (const float*)d_in[0];
    const float* rays_d = (const float*)d_in[1];
    const float* grid   = (const float*)d_in[2];
    const float* atoms  = (const float*)d_in[3];
    float* out   = (float*)d_out;
    float* rgb   = out;                                        // [512,3]
    float* alpha = out + BATCH * 3;                            // [512,383]
    float* depth = out + BATCH * 3 + BATCH * SAMPLES;          // [512]
    float* loss  = out + BATCH * 3 + BATCH * SAMPLES + BATCH;  // scalar

    dp_fused<<<dim3(BATCH), dim3(512), 0, stream>>>(
        rays_o, rays_d, grid, atoms, rgb, alpha, depth, loss);
}

// Round 8
// 16.901 us; speedup vs baseline: 1.7350x; 1.7350x over previous
//
#include <hip/hip_runtime.h>
#include <math.h>

#define R_ 1.3f
#define NCOARSE 32
#define SAMPLES 383
#define BATCH 512
#define STEPSZ 0.0203125f                  // 2*1.3/32/2/2
#define INV_FINE_VLEN 24.615384615384617f  // 64 / 2.6

using f32x4 = __attribute__((ext_vector_type(4))) float;
using s16x8 = __attribute__((ext_vector_type(8))) short;
using u32x4 = __attribute__((ext_vector_type(4))) unsigned int;
using bf16x2 = __attribute__((ext_vector_type(2))) __bf16;

// f32 pair -> packed bf16 (RNE); compiler emits v_cvt_pk_bf16_f32.
__device__ __forceinline__ unsigned int packbf2(float lo, float hi) {
    bf16x2 v;
    v.x = (__bf16)lo;
    v.y = (__bf16)hi;
    return __builtin_bit_cast(unsigned int, v);
}

// Per-dim: summed weight W[t] and coarse index C[t] for fine-parity t.
__device__ __forceinline__ void dimwc(float p, float* W, int* C) {
    float post0 = fminf(fmaxf(floorf(p - 0.5f), 0.f), 63.f);
    float post1 = fminf(fmaxf(floorf(p + 0.5f), 0.f), 63.f);
    float w0 = 1.f - fabsf(p - (post0 + 0.5f));
    float w1 = 1.f - fabsf(p - (post1 + 0.5f));
    int i0 = (int)post0, i1 = (int)post1;
    int f0 = i0 & 1, f1 = i1 & 1;
    W[0] = (f0 == 0 ? w0 : 0.f) + (f1 == 0 ? w1 : 0.f);
    W[1] = (f0 == 1 ? w0 : 0.f) + (f1 == 1 ? w1 : 0.f);
    int c0 = i0 >> 1, c1 = i1 >> 1;
    C[0] = (f0 == 0) ? c0 : c1;
    C[1] = (f0 == 1) ? c0 : c1;
}

// One ray per block, 8 waves. Direct-to-fragment grid gather.
// launch_bounds(512,2): grid=512 gives only 2 blocks/CU anyway -> don't clamp
// the register allocator to 128 VGPR (that forced spills in earlier variants).
__global__ __launch_bounds__(512, 2) void dp_fused(
    const float* __restrict__ rays_o, const float* __restrict__ rays_d,
    const float* __restrict__ grid, const float* __restrict__ atoms,
    float* __restrict__ out_rgb, float* __restrict__ out_alpha,
    float* __restrict__ out_depth, float* __restrict__ out_loss)
{
    __shared__ u32x4 Bf[16][64];        // 16 KB: B fragments (block-shared)
    __shared__ float Dw[8][544];        // 8 waves x 2176 B: D staging (stride 33)
    __shared__ float alpha_l[384];
    __shared__ float sig_l[384][3];
    __shared__ float segtot[8];
    __shared__ float part[6][5];

    const int b = blockIdx.x;
    const int tid = threadIdx.x;
    const int wid = tid >> 6, l = tid & 63;
    const int sl = l & 15, j8 = (l >> 4) * 8;

    // ---- B-build loads FIRST (hide L2 latency under setup) ----
    const int s0i = tid, s1i = tid + 512;
    const int ll0 = s0i & 63, nt0 = (s0i >> 6) & 1, kb0 = s0i >> 7;
    const int ll1 = s1i & 63, nt1 = (s1i >> 6) & 1, kb1 = s1i >> 7;
    const int a00 = (ll0 >> 4) * 8, d0 = nt0 * 16 + (ll0 & 15);
    const int a01 = (ll1 >> 4) * 8, d1 = nt1 * 16 + (ll1 & 15);
    float la0[8], la1[8];
#pragma unroll
    for (int j = 0; j < 8; ++j) {
        la0[j] = (d0 < 28) ? atoms[(kb0 * 32 + a00 + j) * 28 + d0] : 0.f;
        la1[j] = (d1 < 28) ? atoms[(kb1 * 32 + a01 + j) * 28 + d1] : 0.f;
    }

    if (b == 0 && tid == 0) out_loss[0] = 0.f;

    // ---- zero alpha/sig staging ----
    if (tid < 384) alpha_l[tid] = 0.f;
    {
        float* sf = &sig_l[0][0];
        for (int i = tid; i < 384 * 3; i += 512) sf[i] = 0.f;
    }

    // ---- ray setup (block-uniform) ----
    const float ox = rays_o[3 * b], oy = rays_o[3 * b + 1], oz = rays_o[3 * b + 2];
    const float dx = rays_d[3 * b], dy = rays_d[3 * b + 1], dz = rays_d[3 * b + 2];
    const float start = fmaxf(fmaxf(
        fminf((R_ - ox) / dx, (-R_ - ox) / dx),
        fminf((R_ - oy) / dy, (-R_ - oy) / dy)),
        fminf((R_ - oz) / dz, (-R_ - oz) / dz));
    const float t_exit = fminf(fminf(
        fmaxf((R_ - ox) / dx, (-R_ - ox) / dx),
        fmaxf((R_ - oy) / dy, (-R_ - oy) / dy)),
        fmaxf((R_ - oz) / dz, (-R_ - oz) / dz));
    const int ns = (int)floorf((t_exit - start) / STEPSZ) + 2;
    const int ntiles = min(24, (ns >> 4) + 2);

    const float lend = sqrtf(dx * dx + dy * dy + dz * dz);
    const float dist = STEPSZ * lend;
    const float inv = 1.f / lend;
    const float nx = dx * inv, ny = dy * inv, nz = dz * inv;
    float sh[9];
    sh[0] = 0.28209479177387814f;
    sh[1] = -0.48860251190291987f * ny;
    sh[2] = 0.48860251190291987f * nz;
    sh[3] = -0.48860251190291987f * nx;
    sh[4] = 1.0925484305920792f * nx * ny;
    sh[5] = -1.0925484305920792f * ny * nz;
    sh[6] = 0.31539156525252005f * (2.f * nz * nz - nx * nx - ny * ny);
    sh[7] = -1.0925484305920792f * nx * nz;
    sh[8] = 0.5462742152960396f * (nx * nx - ny * ny);

    // ---- pack + store B fragments ----
    {
        u32x4 o0, o1;
#pragma unroll
        for (int e2 = 0; e2 < 4; ++e2) {
            o0[e2] = packbf2(la0[2 * e2], la0[2 * e2 + 1]);
            o1[e2] = packbf2(la1[2 * e2], la1[2 * e2 + 1]);
        }
        Bf[s0i >> 6][ll0] = o0;
        Bf[s1i >> 6][ll1] = o1;
    }

    __syncthreads();   // Bf + zeroed staging visible

    float* Dbuf = &Dw[wid][0];

    // ---- sample phase: wave w handles tiles {w, w+8, w+16} < ntiles ----
    for (int t = wid; t < ntiles; t += 8) {
        const int s = t * 16 + sl;
        const float tt = start + s * STEPSZ;
        const float px = ox + tt * dx, py = oy + tt * dy, pz = oz + tt * dz;
        const bool m = (s < SAMPLES) &&
                       (px > -R_ && px < R_ && py > -R_ && py < R_ && pz > -R_ && pz < R_);
        if (__ballot(m) == 0ull) continue;   // staging pre-zeroed

        float W0[2], W1[2], W2[2];
        int C0[2], C1[2], C2[2];
        dimwc((px + R_) * INV_FINE_VLEN, W0, C0);
        dimwc((py + R_) * INV_FINE_VLEN, W1, C1);
        dimwc((pz + R_) * INV_FINE_VLEN, W2, C2);
        const float msk = m ? 1.f : 0.f;

        f32x4 acc0 = {0.f, 0.f, 0.f, 0.f};
        f32x4 acc1 = {0.f, 0.f, 0.f, 0.f};

        // two halves of 4 corners: direct gather -> scale -> pack -> MFMA
#pragma unroll
        for (int half = 0; half < 2; ++half) {
            f32x4 qa[4], qb[4];
            float wf[4];
#pragma unroll
            for (int k2 = 0; k2 < 4; ++k2) {
                const int kb = half * 4 + k2;
                const int fx = (kb >> 2) & 1, fy = (kb >> 1) & 1, fz = kb & 1;
                wf[k2] = msk * W0[fx] * W1[fy] * W2[fz];
                const int cf = (C0[fx] * NCOARSE + C1[fy]) * NCOARSE + C2[fz];
                const f32x4* gp = (const f32x4*)(grid + cf * 32 + j8);
                qa[k2] = gp[0];
                qb[k2] = gp[1];
            }
#pragma unroll
            for (int k2 = 0; k2 < 4; ++k2) {
                const int kb = half * 4 + k2;
                const float w = wf[k2];
                u32x4 o;
                o.x = packbf2(w * qa[k2].x, w * qa[k2].y);
                o.y = packbf2(w * qa[k2].z, w * qa[k2].w);
                o.z = packbf2(w * qb[k2].x, w * qb[k2].y);
                o.w = packbf2(w * qb[k2].z, w * qb[k2].w);
                const s16x8 af = __builtin_bit_cast(s16x8, o);
                acc0 = __builtin_amdgcn_mfma_f32_16x16x32_bf16(
                    af, __builtin_bit_cast(s16x8, Bf[kb * 2 + 0][l]), acc0, 0, 0, 0);
                acc1 = __builtin_amdgcn_mfma_f32_16x16x32_bf16(
                    af, __builtin_bit_cast(s16x8, Bf[kb * 2 + 1][l]), acc1, 0, 0, 0);
            }
        }

        // D -> LDS, row = sample slot, stride 33 (conflict-free reads)
        const int fp = l >> 4;
#pragma unroll
        for (int r = 0; r < 4; ++r) {
            Dbuf[(4 * fp + r) * 33 + sl]      = acc0[r];
            Dbuf[(4 * fp + r) * 33 + sl + 16] = acc1[r];
        }

        // epilogue: lane -> (sample s2, channel c)
        const int s2 = l >> 2, c = l & 3;
        const int so = t * 16 + s2;
        if (c == 3) {
            const float sigma = fmaxf(Dbuf[s2 * 33 + 27], 0.f);
            alpha_l[so] = 1.f - __expf(-sigma * dist);
        } else {
            float r_ = 0.f;
#pragma unroll
            for (int k = 0; k < 9; ++k) r_ += sh[k] * Dbuf[s2 * 33 + c * 9 + k];
            sig_l[so][c] = __builtin_amdgcn_rcpf(1.f + __expf(-r_));
        }
    }

    __syncthreads();

    // coalesced alpha store
    if (tid < SAMPLES) out_alpha[b * SAMPLES + tid] = alpha_l[tid];

    // ---- parallel compositing: 6 waves each scan a 64-sample segment ----
    float a_s = 0.f, incl = 1.f;
    if (wid < 6) {
        const int s = wid * 64 + l;
        const bool v = s < SAMPLES;
        a_s = v ? alpha_l[s] : 0.f;
        incl = v ? (1.f - a_s + 1e-10f) : 1.f;
#pragma unroll
        for (int off = 1; off < 64; off <<= 1) {
            const float tm = __shfl_up(incl, off, 64);
            if (l >= off) incl *= tm;
        }
        if (l == 63) segtot[wid] = incl;
    }
    __syncthreads();
    if (wid < 6) {
        float pre = 1.f;
        for (int k = 0; k < wid; ++k) pre *= segtot[k];   // wave-uniform
        float excl = __shfl_up(incl, 1, 64);
        if (l == 0) excl = 1.f;
        const int s = wid * 64 + l;
        const bool v = s < SAMPLES;
        const float al = v ? a_s * pre * excl : 0.f;
        float r0 = al * sig_l[s][0];
        float r1 = al * sig_l[s][1];
        float r2 = al * sig_l[s][2];
        float sd = al * (start + s * STEPSZ);
        float sa = al;
#pragma unroll
        for (int m2 = 32; m2 > 0; m2 >>= 1) {
            r0 += __shfl_xor(r0, m2, 64);
            r1 += __shfl_xor(r1, m2, 64);
            r2 += __shfl_xor(r2, m2, 64);
            sd += __shfl_xor(sd, m2, 64);
            sa += __shfl_xor(sa, m2, 64);
        }
        if (l == 0) {
            part[wid][0] = r0; part[wid][1] = r1; part[wid][2] = r2;
            part[wid][3] = sd; part[wid][4] = sa;
        }
    }
    __syncthreads();
    if (tid == 0) {
        float r0 = 0.f, r1 = 0.f, r2 = 0.f, sd = 0.f, sa = 0.f;
#pragma unroll
        for (int j = 0; j < 6; ++j) {
            r0 += part[j][0]; r1 += part[j][1]; r2 += part[j][2];
            sd += part[j][3]; sa += part[j][4];
        }
        const float base = 1.f - sa;
        out_rgb[b * 3 + 0] = r0 + base;
        out_rgb[b * 3 + 1] = r1 + base;
        out_rgb[b * 3 + 2] = r2 + base;
        out_depth[b] = sd;
    }
}

extern "C" void kernel_launch(void* const* d_in, const int* in_sizes, int n_in,
                              void* d_out, int out_size, void* d_ws, size_t ws_size,
                              hipStream_t stream) {
    const float* rays_o = (const float*)d_in[0];
    const float* rays_d = (const float*)d_in[1];
    const float* grid   = (const float*)d_in[2];
    const float* atoms  = (const float*)d_in[3];
    float* out   = (float*)d_out;
    float* rgb   = out;                                        // [512,3]
    float* alpha = out + BATCH * 3;                            // [512,383]
    float* depth = out + BATCH * 3 + BATCH * SAMPLES;          // [512]
    float* loss  = out + BATCH * 3 + BATCH * SAMPLES + BATCH;  // scalar

    dp_fused<<<dim3(BATCH), dim3(512), 0, stream>>>(
        rays_o, rays_d, grid, atoms, rgb, alpha, depth, loss);
}